// Round 16
// baseline (1489.209 us; speedup 1.0000x reference)
//
#include <hip/hip_runtime.h>

// Problem constants (from reference): B=256, T=2048, I=12, H=64
constexpr int Bn = 256;
constexpr int Tn = 2048;
constexpr int In = 12;
constexpr int Hn = 64;
constexpr int TCH = 512;     // steps per staged x quarter
constexpr int CHUNK = 16;    // fc-flush granularity == hist depth

constexpr float LOG2E = 1.44269504088896340736f;

__device__ __forceinline__ float frcp(float v) { return __builtin_amdgcn_rcpf(v); }

// quad_perm DPP: cross-lane move within each group of 4 lanes, pure VALU.
// 0xB1 = [1,0,3,2] = swap adjacent lane pairs.
template <int CTRL>
__device__ __forceinline__ float dppq(float v) {
    int i = __float_as_int(v);
    i = __builtin_amdgcn_mov_dpp(i, CTRL, 0xF, 0xF, false);
    return __int_as_float(i);
}

// Round-16: 2 waves (128 threads), FULL-K rows, no reduce phase.
//   Lane pair (2k, 2k+1) of wave w owns h-index j = 32w + k.
//   even lane: rows {j, 64+j}   (gates i, f) — both sigmoid
//   odd  lane: rows {128+j, 192+j} (gates g, o) — tanh, sigmoid
//   Each lane: 2 full dots over h[64] (128 FMA) + x (24 FMA). The dot
//   COMPLETES in-lane -> activation immediately; i/f/g/o exchange = one
//   DPP pair-swap per act register; c,h computed in the even lane; h
//   published with a single ds_write. ONE barrier per step.
//   (Round 15 lesson: extra waves on the same barrier-locked chain don't
//   overlap anything — shorten the chain instead. This removes the
//   cross-wave partial reduce (~190 cyc) and the 16-readlane fan (~35)
//   at the cost of +144 cyc FMA issue — net ~-280 on the chain, and at
//   2 waves the full-h broadcast reads (~160 LDS-pipe cyc) hide under
//   the FMA stream instead of saturating the pipe like round 10's
//   4-wave full-K did.)
extern "C" __global__ void __launch_bounds__(128, 1)
lstm_fused_kernel(const float* __restrict__ x,
                  const float* __restrict__ w_ih,
                  const float* __restrict__ w_hh,
                  const float* __restrict__ b_ih,
                  const float* __restrict__ b_hh,
                  const float* __restrict__ fc_w,
                  const float* __restrict__ fc_b,
                  float* __restrict__ out)
{
    __shared__ __align__(16) float xbuf[TCH * In];      // 24 KiB (x quarter)
    __shared__ __align__(16) float hbuf[2][Hn];         // h ping-pong
    __shared__ __align__(16) float hist[2][CHUNK][Hn];  // 8 KiB fc history

    const int tid  = threadIdx.x;       // 0..127
    const int lane = tid & 63;
    const int w    = tid >> 6;          // wave 0..1
    const int pr   = lane & 1;          // 0: gates {i,f}, 1: gates {g,o}
    const int j    = 32 * w + (lane >> 1);   // owned h index
    const int row0 = (pr ? 128 : 0) + j;     // gate (2*pr)   row
    const int row1 = row0 + 64;              // gate (2*pr+1) row
    const int b    = blockIdx.x;

    const float4* xsrc4 = (const float4*)(x + (size_t)b * Tn * In);

    // ---- per-lane full weight rows in registers (128 VGPR) ----
    float wh0[Hn], wh1[Hn];
    {
        const float4* s0 = (const float4*)(w_hh + row0 * Hn);
        const float4* s1 = (const float4*)(w_hh + row1 * Hn);
        #pragma unroll
        for (int k = 0; k < 16; ++k) {
            float4 v = s0[k];
            wh0[4*k]=v.x; wh0[4*k+1]=v.y; wh0[4*k+2]=v.z; wh0[4*k+3]=v.w;
        }
        #pragma unroll
        for (int k = 0; k < 16; ++k) {
            float4 v = s1[k];
            wh1[4*k]=v.x; wh1[4*k+1]=v.y; wh1[4*k+2]=v.z; wh1[4*k+3]=v.w;
        }
    }
    #pragma unroll
    for (int k = 0; k < Hn; k += 4) {
        asm volatile("" : "+v"(wh0[k]), "+v"(wh0[k+1]), "+v"(wh0[k+2]), "+v"(wh0[k+3]));
        asm volatile("" : "+v"(wh1[k]), "+v"(wh1[k+1]), "+v"(wh1[k+2]), "+v"(wh1[k+3]));
    }
    float wi0[In], wi1[In];
    {
        const float4* s0 = (const float4*)(w_ih + row0 * In);   // 48B rows, aligned
        const float4* s1 = (const float4*)(w_ih + row1 * In);
        #pragma unroll
        for (int k = 0; k < 3; ++k) {
            float4 v = s0[k];
            wi0[4*k]=v.x; wi0[4*k+1]=v.y; wi0[4*k+2]=v.z; wi0[4*k+3]=v.w;
        }
        #pragma unroll
        for (int k = 0; k < 3; ++k) {
            float4 v = s1[k];
            wi1[4*k]=v.x; wi1[4*k+1]=v.y; wi1[4*k+2]=v.z; wi1[4*k+3]=v.w;
        }
    }
    #pragma unroll
    for (int k = 0; k < In; k += 4) {
        asm volatile("" : "+v"(wi0[k]), "+v"(wi0[k+1]), "+v"(wi0[k+2]), "+v"(wi0[k+3]));
        asm volatile("" : "+v"(wi1[k]), "+v"(wi1[k+1]), "+v"(wi1[k+2]), "+v"(wi1[k+3]));
    }

    const float bias0 = b_ih[row0] + b_hh[row0];
    const float bias1 = b_ih[row1] + b_hh[row1];
    // row0 activation: even = sigmoid, odd = tanh (= 2*sig(2a)-1)
    const float m0  = pr ? 2.0f : 1.0f;
    const float o0  = pr ? -1.0f : 0.0f;
    const float me0 = pr ? (-2.0f * LOG2E) : (-LOG2E);
    // row1 activation: always sigmoid.

    // fc flush constants: thread (fs, fe) covers h[8fe..8fe+8) of step fs
    const int   fs  = tid >> 3;          // 0..15
    const int   fe  = tid & 7;           // 0..7
    const float4 fwa = *(const float4*)(fc_w + 8 * fe);
    const float4 fwb = *(const float4*)(fc_w + 8 * fe + 4);
    const float fcb = fc_b[0];

    float c = 0.0f;                      // cell state (valid in even lanes)
    if (tid < Hn) hbuf[1][tid] = 0.0f;   // h_{-1} = 0 (step 0 reads hbuf[1])

    float* outb = out + (size_t)b * Tn;

    for (int ci = 0; ci < Tn / CHUNK; ++ci) {
        const int T0  = ci * CHUNK;
        const int par = ci & 1;

        // ---- stage x quarter (prev quarter fully consumed pre-barrier) ----
        if ((T0 & (TCH - 1)) == 0) {
            const int qtr = T0 >> 9;                 // T0 / TCH
            #pragma unroll
            for (int k = 0; k < 12; ++k) {
                int li = tid + k * 128;              // 0..1535 float4s
                ((float4*)xbuf)[li] = xsrc4[qtr * 1536 + li];
            }
            __syncthreads();
        }

        #pragma unroll
        for (int s = 0; s < CHUNK; ++s) {
            const int t  = T0 + s;
            const int tl = t & (TCH - 1);

            // x row (uniform -> LDS broadcast), off the h-chain
            const float* xr = xbuf + tl * In;
            float4 xa = *(const float4*)(xr);
            float4 xb = *(const float4*)(xr + 4);
            float4 xc = *(const float4*)(xr + 8);

            float a0 = bias0, a1 = bias1;
            // full h[64] read: 16 uniform b128 (broadcast), pipelined into FMAs
            const float4* hp = (const float4*)hbuf[(t & 1) ^ 1];
            #pragma unroll
            for (int k = 0; k < 16; ++k) {
                float4 hv = hp[k];
                a0 = fmaf(hv.x, wh0[4*k+0], a0);  a1 = fmaf(hv.x, wh1[4*k+0], a1);
                a0 = fmaf(hv.y, wh0[4*k+1], a0);  a1 = fmaf(hv.y, wh1[4*k+1], a1);
                a0 = fmaf(hv.z, wh0[4*k+2], a0);  a1 = fmaf(hv.z, wh1[4*k+2], a1);
                a0 = fmaf(hv.w, wh0[4*k+3], a0);  a1 = fmaf(hv.w, wh1[4*k+3], a1);
            }
            // x contribution (independent of h -> fills h-read latency)
            a0 = fmaf(xa.x, wi0[0],  a0);  a1 = fmaf(xa.x, wi1[0],  a1);
            a0 = fmaf(xa.y, wi0[1],  a0);  a1 = fmaf(xa.y, wi1[1],  a1);
            a0 = fmaf(xa.z, wi0[2],  a0);  a1 = fmaf(xa.z, wi1[2],  a1);
            a0 = fmaf(xa.w, wi0[3],  a0);  a1 = fmaf(xa.w, wi1[3],  a1);
            a0 = fmaf(xb.x, wi0[4],  a0);  a1 = fmaf(xb.x, wi1[4],  a1);
            a0 = fmaf(xb.y, wi0[5],  a0);  a1 = fmaf(xb.y, wi1[5],  a1);
            a0 = fmaf(xb.z, wi0[6],  a0);  a1 = fmaf(xb.z, wi1[6],  a1);
            a0 = fmaf(xb.w, wi0[7],  a0);  a1 = fmaf(xb.w, wi1[7],  a1);
            a0 = fmaf(xc.x, wi0[8],  a0);  a1 = fmaf(xc.x, wi1[8],  a1);
            a0 = fmaf(xc.y, wi0[9],  a0);  a1 = fmaf(xc.y, wi1[9],  a1);
            a0 = fmaf(xc.z, wi0[10], a0);  a1 = fmaf(xc.z, wi1[10], a1);
            a0 = fmaf(xc.w, wi0[11], a0);  a1 = fmaf(xc.w, wi1[11], a1);

            // activations: even (sig,sig) = (i,f); odd (tanh,sig) = (g,o)
            float e0   = exp2f(me0 * a0);
            float act0 = fmaf(m0, frcp(1.0f + e0), o0);
            float e1   = exp2f(-LOG2E * a1);
            float act1 = frcp(1.0f + e1);

            // pair exchange: even lane receives (g, o) from odd partner
            float p0 = dppq<0xB1>(act0);
            float p1 = dppq<0xB1>(act1);

            // even lanes: i=act0, f=act1, g=p0, o=p1  (odd lanes: garbage, unused)
            c = fmaf(act1, c, act0 * p0);
            float ec = exp2f(-2.0f * LOG2E * c);
            float h  = p1 * fmaf(2.0f, frcp(1.0f + ec), -1.0f);

            if (!pr) {
                hbuf[t & 1][j]  = h;     // recurrence publish
                hist[par][s][j] = h;     // fc history
            }
            __syncthreads();             // the ONE barrier per step
        }

        // ---- fc flush: 128 threads reduce hist[par][16][64] -> 16 outputs ----
        // hist ping-pong: next chunk writes hist[par^1], so no extra barrier.
        {
            const float4 hv0 = *(const float4*)(&hist[par][fs][8 * fe]);
            const float4 hv1 = *(const float4*)(&hist[par][fs][8 * fe + 4]);
            float pp = hv0.x * fwa.x + hv0.y * fwa.y + hv0.z * fwa.z + hv0.w * fwa.w
                     + hv1.x * fwb.x + hv1.y * fwb.y + hv1.z * fwb.z + hv1.w * fwb.w;
            pp += __shfl_xor(pp, 1, 8);
            pp += __shfl_xor(pp, 2, 8);
            pp += __shfl_xor(pp, 4, 8);
            if (fe == 0) outb[T0 + fs] = pp + fcb;   // fire-and-forget
        }
    }
}

extern "C" void kernel_launch(void* const* d_in, const int* in_sizes, int n_in,
                              void* d_out, int out_size, void* d_ws, size_t ws_size,
                              hipStream_t stream) {
    const float* x    = (const float*)d_in[0];
    const float* w_ih = (const float*)d_in[1];
    const float* w_hh = (const float*)d_in[2];
    const float* b_ih = (const float*)d_in[3];
    const float* b_hh = (const float*)d_in[4];
    const float* fc_w = (const float*)d_in[5];
    const float* fc_b = (const float*)d_in[6];
    float* out = (float*)d_out;

    lstm_fused_kernel<<<Bn, 128, 0, stream>>>(x, w_ih, w_hh, b_ih, b_hh,
                                              fc_w, fc_b, out);
}

// Round 18
// 994.043 us; speedup vs baseline: 1.4981x; 1.4981x over previous
//
#include <hip/hip_runtime.h>

// Problem constants (from reference): B=256, T=2048, I=12, H=64
constexpr int Bn = 256;
constexpr int Tn = 2048;
constexpr int In = 12;
constexpr int Hn = 64;
constexpr int TCH = 256;     // steps per staged x chunk (per chain)
constexpr int CHUNK = 16;    // fc-flush granularity == hist depth

constexpr int XBUF = TCH * 16;      // 4096 floats / chain (x padded to 16)
constexpr int PBUF = 2 * 4 * 256;   // 2048 floats / chain
constexpr int HIST = CHUNK * Hn;    // 1024 floats / chain

constexpr float LOG2E = 1.44269504088896340736f;

__device__ __forceinline__ float frcp(float v) { return __builtin_amdgcn_rcpf(v); }

template <int CTRL>
__device__ __forceinline__ float dppq(float v) {
    int i = __float_as_int(v);
    i = __builtin_amdgcn_mov_dpp(i, CTRL, 0xF, 0xF, false);
    return __int_as_float(i);
}
__device__ __forceinline__ float rdl(float v, int l) {
    return __int_as_float(__builtin_amdgcn_readlane(__float_as_int(v), l));
}

// Round-18 = round-17 (two independent r14-chains per block) + the
// __syncthreads() before the fc flush that r17 erroneously dropped.
// The hist write for step 15 happens AFTER the step-15 barrier (reduce
// phase), so the flush needs its own barrier to see other waves' writes
// (r14 had it; r17's removal caused absmax 0.13 on the chunk-tail steps).
extern "C" __global__ void __launch_bounds__(512, 1)
lstm_fused_kernel(const float* __restrict__ x,
                  const float* __restrict__ w_ih,
                  const float* __restrict__ w_hh,
                  const float* __restrict__ b_ih,
                  const float* __restrict__ b_hh,
                  const float* __restrict__ fc_w,
                  const float* __restrict__ fc_b,
                  float* __restrict__ out)
{
    __shared__ __align__(16) float xbuf[2 * XBUF];   // 32 KiB
    __shared__ __align__(16) float pbuf[2 * PBUF];   // 16 KiB
    __shared__ __align__(16) float hist[2 * HIST];   //  8 KiB

    const int tid   = threadIdx.x;       // 0..511
    const int chain = tid >> 8;          // 0 or 1
    const int lt    = tid & 255;         // tid within chain
    const int lane  = lt & 63;
    const int w     = lt >> 6;           // wave-in-chain 0..3
    const int g     = lane & 3;          // gate type 0:i 1:f 2:g 3:o
    const int i16   = lane >> 2;         // 0..15
    const int jown  = 16 * w + i16;      // owned h index
    const int ro    = 64 * g + jown;     // reduce-phase row
    const int b     = 2 * blockIdx.x + chain;

    const int wbase = ((lane >> 2) & 3) * 64 + (lane >> 4) * 16 + 4 * (lane & 3);
    const int rbase = w * 64 + g * 16 + i16;

    float* xb  = xbuf + chain * XBUF;
    float* pb2 = pbuf + chain * PBUF;
    float* hb  = hist + chain * HIST;

    const float4* xsrc4 = (const float4*)(x + (size_t)b * Tn * In);

    // ---- zero the x padding columns (i = 12..15) once ----
    ((float4*)xb)[lt * 4 + 3] = float4{0.f, 0.f, 0.f, 0.f};

    // ---- per-lane weight slices (rows 4*lane..+3, K-slice of wave) ----
    float whh_s[4][16];
    #pragma unroll
    for (int r = 0; r < 4; ++r) {
        const float4* src = (const float4*)(w_hh + (4 * lane + r) * Hn + 16 * w);
        float4 v0 = src[0], v1 = src[1], v2 = src[2], v3 = src[3];
        whh_s[r][0]=v0.x;  whh_s[r][1]=v0.y;  whh_s[r][2]=v0.z;  whh_s[r][3]=v0.w;
        whh_s[r][4]=v1.x;  whh_s[r][5]=v1.y;  whh_s[r][6]=v1.z;  whh_s[r][7]=v1.w;
        whh_s[r][8]=v2.x;  whh_s[r][9]=v2.y;  whh_s[r][10]=v2.z; whh_s[r][11]=v2.w;
        whh_s[r][12]=v3.x; whh_s[r][13]=v3.y; whh_s[r][14]=v3.z; whh_s[r][15]=v3.w;
    }
    #pragma unroll
    for (int r = 0; r < 4; ++r)
        #pragma unroll
        for (int k = 0; k < 16; k += 4)
            asm volatile("" : "+v"(whh_s[r][k+0]), "+v"(whh_s[r][k+1]),
                              "+v"(whh_s[r][k+2]), "+v"(whh_s[r][k+3]));

    float wih_s[4][4];
    if (w < 3) {
        #pragma unroll
        for (int r = 0; r < 4; ++r) {
            float4 v = *(const float4*)(w_ih + (4 * lane + r) * In + 4 * w);
            wih_s[r][0]=v.x; wih_s[r][1]=v.y; wih_s[r][2]=v.z; wih_s[r][3]=v.w;
        }
    } else {
        #pragma unroll
        for (int r = 0; r < 4; ++r)
            wih_s[r][0]=wih_s[r][1]=wih_s[r][2]=wih_s[r][3]=0.0f;
    }
    #pragma unroll
    for (int r = 0; r < 4; ++r)
        asm volatile("" : "+v"(wih_s[r][0]), "+v"(wih_s[r][1]),
                          "+v"(wih_s[r][2]), "+v"(wih_s[r][3]));

    const float bias = b_ih[ro] + b_hh[ro];
    // act = scl * sigma(scl*a) + soff:  g!=2 -> sigma(a);  g==2 -> tanh(a)
    const float scl  = (g == 2) ? 2.0f : 1.0f;
    const float soff = (g == 2) ? -1.0f : 0.0f;
    const float me   = (g == 2) ? (-2.0f * LOG2E) : (-LOG2E);
    // fc flush constants (within chain)
    const int   fq   = lt & 15;
    const int   fs   = lt >> 4;          // 0..15
    const float4 fw4 = *(const float4*)(fc_w + 4 * fq);
    const float fcb  = fc_b[0];

    float h_own = 0.0f;                  // h[jown] (quad-redundant)
    float c     = 0.0f;                  // cell state for jown

    float* outb = out + (size_t)b * Tn;

    for (int ci = 0; ci < Tn / CHUNK; ++ci) {
        const int T0 = ci * CHUNK;

        // ---- stage x chunk (256 steps, 768 float4 per chain) ----
        if ((T0 & (TCH - 1)) == 0) {
            const int qtr = T0 >> 8;                  // 0..7
            #pragma unroll
            for (int k = 0; k < 3; ++k) {
                int li  = lt + k * 256;               // 0..767
                int t_l = li / 3;
                int i4  = li % 3;
                ((float4*)xb)[t_l * 4 + i4] = xsrc4[qtr * 768 + li];
            }
            __syncthreads();
        }

        #pragma unroll
        for (int s = 0; s < CHUNK; ++s) {
            const int tl = (T0 + s) & (TCH - 1);

            // ---- SGPR h-broadcast (quad lane 4k holds h[16w+k]) ----
            float hs0  = rdl(h_own,  0), hs1  = rdl(h_own,  4);
            float hs2  = rdl(h_own,  8), hs3  = rdl(h_own, 12);
            float hs4  = rdl(h_own, 16), hs5  = rdl(h_own, 20);
            float hs6  = rdl(h_own, 24), hs7  = rdl(h_own, 28);
            float hs8  = rdl(h_own, 32), hs9  = rdl(h_own, 36);
            float hs10 = rdl(h_own, 40), hs11 = rdl(h_own, 44);
            float hs12 = rdl(h_own, 48), hs13 = rdl(h_own, 52);
            float hs14 = rdl(h_own, 56), hs15 = rdl(h_own, 60);

            // ---- partial phase: rows 4*lane..4*lane+3 over wave's K-slice ----
            const float4 xv = *(const float4*)(xb + tl * 16 + 4 * w);
            float p0 = hs0 * whh_s[0][0], p1 = hs0 * whh_s[1][0];
            float p2 = hs0 * whh_s[2][0], p3 = hs0 * whh_s[3][0];
            #define HFMA(K, HS) \
                p0 = fmaf(HS, whh_s[0][K], p0);  p1 = fmaf(HS, whh_s[1][K], p1); \
                p2 = fmaf(HS, whh_s[2][K], p2);  p3 = fmaf(HS, whh_s[3][K], p3);
            HFMA(1,  hs1)  HFMA(2,  hs2)  HFMA(3,  hs3)
            HFMA(4,  hs4)  HFMA(5,  hs5)  HFMA(6,  hs6)  HFMA(7,  hs7)
            HFMA(8,  hs8)  HFMA(9,  hs9)  HFMA(10, hs10) HFMA(11, hs11)
            HFMA(12, hs12) HFMA(13, hs13) HFMA(14, hs14) HFMA(15, hs15)
            #undef HFMA
            p0 = fmaf(xv.x, wih_s[0][0], p0);  p1 = fmaf(xv.x, wih_s[1][0], p1);
            p2 = fmaf(xv.x, wih_s[2][0], p2);  p3 = fmaf(xv.x, wih_s[3][0], p3);
            p0 = fmaf(xv.y, wih_s[0][1], p0);  p1 = fmaf(xv.y, wih_s[1][1], p1);
            p2 = fmaf(xv.y, wih_s[2][1], p2);  p3 = fmaf(xv.y, wih_s[3][1], p3);
            p0 = fmaf(xv.z, wih_s[0][2], p0);  p1 = fmaf(xv.z, wih_s[1][2], p1);
            p2 = fmaf(xv.z, wih_s[2][2], p2);  p3 = fmaf(xv.z, wih_s[3][2], p3);
            p0 = fmaf(xv.w, wih_s[0][3], p0);  p1 = fmaf(xv.w, wih_s[1][3], p1);
            p2 = fmaf(xv.w, wih_s[2][3], p2);  p3 = fmaf(xv.w, wih_s[3][3], p3);

            float4 pv; pv.x = p0; pv.y = p1; pv.z = p2; pv.w = p3;
            *(float4*)(pb2 + (s & 1) * 1024 + w * 256 + wbase) = pv;
            __syncthreads();               // the ONE barrier per step

            // ---- reduce phase: own row ro (conflict-free reads) ----
            const float* pr = pb2 + (s & 1) * 1024;
            float a = ((pr[rbase] + pr[256 + rbase]) +
                       (pr[512 + rbase] + pr[768 + rbase])) + bias;
            float e   = exp2f(me * a);
            float act = fmaf(scl, frcp(1.0f + e), soff);

            float iv = dppq<0x00>(act);
            float fv = dppq<0x55>(act);
            float gv = dppq<0xAA>(act);
            float ov = dppq<0xFF>(act);

            c = fmaf(fv, c, iv * gv);
            float e2 = exp2f(-2.0f * LOG2E * c);
            h_own = ov * fmaf(2.0f, frcp(1.0f + e2), -1.0f);

            if (g == 0) hb[s * Hn + jown] = h_own;     // fc history only
        }

        // ---- fc flush: needs all waves' hist writes of this chunk ----
        __syncthreads();
        {
            const float4 hv = *(const float4*)(hb + fs * Hn + 4 * fq);
            float pp = hv.x * fw4.x + hv.y * fw4.y + hv.z * fw4.z + hv.w * fw4.w;
            #pragma unroll
            for (int off = 8; off; off >>= 1)
                pp += __shfl_xor(pp, off, 16);
            if (fq == 0) outb[T0 + fs] = pp + fcb;
        }
    }
}

extern "C" void kernel_launch(void* const* d_in, const int* in_sizes, int n_in,
                              void* d_out, int out_size, void* d_ws, size_t ws_size,
                              hipStream_t stream) {
    const float* x    = (const float*)d_in[0];
    const float* w_ih = (const float*)d_in[1];
    const float* w_hh = (const float*)d_in[2];
    const float* b_ih = (const float*)d_in[3];
    const float* b_hh = (const float*)d_in[4];
    const float* fc_w = (const float*)d_in[5];
    const float* fc_b = (const float*)d_in[6];
    float* out = (float*)d_out;

    lstm_fused_kernel<<<Bn / 2, 512, 0, stream>>>(x, w_ih, w_hh, b_ih, b_hh,
                                                  fc_w, fc_b, out);
}

// Round 19
// 874.295 us; speedup vs baseline: 1.7033x; 1.1370x over previous
//
#include <hip/hip_runtime.h>

// Problem constants (from reference): B=256, T=2048, I=12, H=64
constexpr int Bn = 256;
constexpr int Tn = 2048;
constexpr int In = 12;
constexpr int Hn = 64;
constexpr int TCH = 512;     // steps per staged x quarter (padded to 16)
constexpr int CHUNK = 16;    // fc-flush granularity == hist depth

constexpr float LOG2E = 1.44269504088896340736f;

__device__ __forceinline__ float frcp(float v) { return __builtin_amdgcn_rcpf(v); }

// quad_perm DPP: cross-lane move within each group of 4 lanes, pure VALU.
// 0xB1 = [1,0,3,2] (xor 1), 0x4E = [2,3,0,1] (xor 2).
template <int CTRL>
__device__ __forceinline__ float dppq(float v) {
    int i = __float_as_int(v);
    i = __builtin_amdgcn_mov_dpp(i, CTRL, 0xF, 0xF, false);
    return __int_as_float(i);
}

// Round-19: quad-K-split + DPP butterfly. 256 threads, 4 waves, 256 blocks.
//   lane = 4*j4 + ks (ks = lane&3, j4 = lane>>2); wave w owns h-indices
//   j = 16w + j4. Lane computes partials for the 4 GATE ROWS of its one
//   h-index {j, 64+j, 128+j, 192+j} over K-slice [16ks, 16ks+16):
//   64 h-FMA + 16 x-FMA. Then a 2-stage quad_perm butterfly (xor1, xor2)
//   completes all 4 gate sums IN-LANE — no cross-wave partial reduce, no
//   pbuf LDS round-trip (r14's ~200cyc), no readlane fan (~35cyc).
//   All activations + c + h computed in-lane (quad-redundant); ks==0 lane
//   publishes h[j]; ONE end-of-step barrier; next step reads the K-slice
//   as 4 uniform b128 (2-way bank aliasing = free, m136).
//   Barrier placement AFTER the hist write also makes the per-chunk fc
//   flush safe with NO extra barrier (hist ping-pong, r17's bug avoided).
extern "C" __global__ void __launch_bounds__(256, 1)
lstm_fused_kernel(const float* __restrict__ x,
                  const float* __restrict__ w_ih,
                  const float* __restrict__ w_hh,
                  const float* __restrict__ b_ih,
                  const float* __restrict__ b_hh,
                  const float* __restrict__ fc_w,
                  const float* __restrict__ fc_b,
                  float* __restrict__ out)
{
    __shared__ __align__(16) float xbuf[TCH * 16];        // 32 KiB (x quarter)
    __shared__ __align__(16) float hbuf[2][Hn];           // ping-pong h
    __shared__ __align__(16) float hist[2][CHUNK][Hn];    // 8 KiB fc history

    const int tid  = threadIdx.x;       // 0..255
    const int lane = tid & 63;
    const int w    = tid >> 6;          // wave id 0..3
    const int ks   = lane & 3;          // K-slice id
    const int j4   = lane >> 2;         // 0..15
    const int j    = 16 * w + j4;       // owned h index
    const int b    = blockIdx.x;

    const float4* xsrc4 = (const float4*)(x + (size_t)b * Tn * In);

    // ---- zero the x padding columns (i = 12..15) once ----
    #pragma unroll
    for (int k = 0; k < 8; ++k) {
        int idx = tid + k * 256;                       // 0..2047
        xbuf[(idx >> 2) * 16 + 12 + (idx & 3)] = 0.0f;
    }

    // ---- per-lane weights: 4 gate rows of h-index j, K-slice of ks ----
    float whh_s[4][16];
    #pragma unroll
    for (int m = 0; m < 4; ++m) {
        const float4* src = (const float4*)(w_hh + (64 * m + j) * Hn + 16 * ks);
        float4 v0 = src[0], v1 = src[1], v2 = src[2], v3 = src[3];
        whh_s[m][0]=v0.x;  whh_s[m][1]=v0.y;  whh_s[m][2]=v0.z;  whh_s[m][3]=v0.w;
        whh_s[m][4]=v1.x;  whh_s[m][5]=v1.y;  whh_s[m][6]=v1.z;  whh_s[m][7]=v1.w;
        whh_s[m][8]=v2.x;  whh_s[m][9]=v2.y;  whh_s[m][10]=v2.z; whh_s[m][11]=v2.w;
        whh_s[m][12]=v3.x; whh_s[m][13]=v3.y; whh_s[m][14]=v3.z; whh_s[m][15]=v3.w;
    }
    #pragma unroll
    for (int m = 0; m < 4; ++m)
        #pragma unroll
        for (int k = 0; k < 16; k += 4)
            asm volatile("" : "+v"(whh_s[m][k+0]), "+v"(whh_s[m][k+1]),
                              "+v"(whh_s[m][k+2]), "+v"(whh_s[m][k+3]));

    float wih_s[4][4];
    if (ks < 3) {
        #pragma unroll
        for (int m = 0; m < 4; ++m) {
            float4 v = *(const float4*)(w_ih + (64 * m + j) * In + 4 * ks);
            wih_s[m][0]=v.x; wih_s[m][1]=v.y; wih_s[m][2]=v.z; wih_s[m][3]=v.w;
        }
    } else {
        #pragma unroll
        for (int m = 0; m < 4; ++m)
            wih_s[m][0]=wih_s[m][1]=wih_s[m][2]=wih_s[m][3]=0.0f;
    }
    #pragma unroll
    for (int m = 0; m < 4; ++m)
        asm volatile("" : "+v"(wih_s[m][0]), "+v"(wih_s[m][1]),
                          "+v"(wih_s[m][2]), "+v"(wih_s[m][3]));

    // bias folded into ks==0 lane's accumulator init (summed by butterfly)
    float bias[4];
    #pragma unroll
    for (int m = 0; m < 4; ++m)
        bias[m] = (ks == 0) ? (b_ih[64 * m + j] + b_hh[64 * m + j]) : 0.0f;

    // fc flush constants
    const int   fq  = tid & 15;
    const int   fs  = tid >> 4;          // 0..15
    const float4 fw4 = *(const float4*)(fc_w + 4 * fq);
    const float fcb = fc_b[0];

    float c = 0.0f;                      // cell state for j (quad-redundant)
    if (tid < Hn) hbuf[1][tid] = 0.0f;   // h_{-1} = 0 (step 0 reads hbuf[1])
    __syncthreads();

    float* outb = out + (size_t)b * Tn;

    for (int ci = 0; ci < Tn / CHUNK; ++ci) {
        const int T0  = ci * CHUNK;
        const int par = ci & 1;

        // ---- stage x quarter (prev quarter fully consumed pre-barrier) ----
        if ((T0 & (TCH - 1)) == 0) {
            const int qtr = T0 >> 9;
            #pragma unroll
            for (int k = 0; k < 6; ++k) {
                int li  = tid + k * 256;              // 0..1535 (float4s)
                int t_l = li / 3;
                int i4  = li % 3;
                ((float4*)xbuf)[t_l * 4 + i4] = xsrc4[qtr * 1536 + li];
            }
            __syncthreads();
        }

        #pragma unroll
        for (int s = 0; s < CHUNK; ++s) {
            const int tl = (T0 + s) & (TCH - 1);

            // ---- reads: x slice + own h K-slice (uniform per quad-group) ----
            const float4 xv = *(const float4*)(xbuf + tl * 16 + 4 * ks);
            const float4* hp = (const float4*)hbuf[(s & 1) ^ 1] + 4 * ks;
            float4 h0 = hp[0], h1 = hp[1], h2 = hp[2], h3 = hp[3];

            float a0 = bias[0], a1 = bias[1], a2 = bias[2], a3 = bias[3];
            // x contribution (independent of h)
            a0 = fmaf(xv.x, wih_s[0][0], a0);  a1 = fmaf(xv.x, wih_s[1][0], a1);
            a2 = fmaf(xv.x, wih_s[2][0], a2);  a3 = fmaf(xv.x, wih_s[3][0], a3);
            a0 = fmaf(xv.y, wih_s[0][1], a0);  a1 = fmaf(xv.y, wih_s[1][1], a1);
            a2 = fmaf(xv.y, wih_s[2][1], a2);  a3 = fmaf(xv.y, wih_s[3][1], a3);
            a0 = fmaf(xv.z, wih_s[0][2], a0);  a1 = fmaf(xv.z, wih_s[1][2], a1);
            a2 = fmaf(xv.z, wih_s[2][2], a2);  a3 = fmaf(xv.z, wih_s[3][2], a3);
            a0 = fmaf(xv.w, wih_s[0][3], a0);  a1 = fmaf(xv.w, wih_s[1][3], a1);
            a2 = fmaf(xv.w, wih_s[2][3], a2);  a3 = fmaf(xv.w, wih_s[3][3], a3);
            // h contribution: 64 FMA over the K-slice
            #define HF(HV, K) \
                a0 = fmaf(HV, whh_s[0][K], a0);  a1 = fmaf(HV, whh_s[1][K], a1); \
                a2 = fmaf(HV, whh_s[2][K], a2);  a3 = fmaf(HV, whh_s[3][K], a3);
            HF(h0.x, 0)  HF(h0.y, 1)  HF(h0.z, 2)  HF(h0.w, 3)
            HF(h1.x, 4)  HF(h1.y, 5)  HF(h1.z, 6)  HF(h1.w, 7)
            HF(h2.x, 8)  HF(h2.y, 9)  HF(h2.z, 10) HF(h2.w, 11)
            HF(h3.x, 12) HF(h3.y, 13) HF(h3.z, 14) HF(h3.w, 15)
            #undef HF

            // ---- quad butterfly: complete the K-sum in-lane (pure VALU) ----
            a0 += dppq<0xB1>(a0);  a1 += dppq<0xB1>(a1);
            a2 += dppq<0xB1>(a2);  a3 += dppq<0xB1>(a3);
            a0 += dppq<0x4E>(a0);  a1 += dppq<0x4E>(a1);
            a2 += dppq<0x4E>(a2);  a3 += dppq<0x4E>(a3);

            // ---- activations (all in-lane, independent -> ILP) ----
            float ei = exp2f(-LOG2E * a0);         float iv = frcp(1.0f + ei);
            float ef = exp2f(-LOG2E * a1);         float fv = frcp(1.0f + ef);
            float eg = exp2f(-2.0f * LOG2E * a2);  float gv = fmaf(2.0f, frcp(1.0f + eg), -1.0f);
            float eo = exp2f(-LOG2E * a3);         float ov = frcp(1.0f + eo);

            c = fmaf(fv, c, iv * gv);
            float ec = exp2f(-2.0f * LOG2E * c);
            float h  = ov * fmaf(2.0f, frcp(1.0f + ec), -1.0f);

            if (ks == 0) {
                hbuf[s & 1][j]    = h;   // recurrence publish
                hist[par][s][j]   = h;   // fc history
            }
            __syncthreads();             // the ONE barrier per step
        }

        // ---- fc flush: hist[par] complete as of the last step barrier ----
        // No extra barrier: next chunk writes hist[par^1]; reuse of
        // hist[par] is fenced by that chunk's 16 step barriers.
        {
            const float4 hv = *(const float4*)(&hist[par][fs][4 * fq]);
            float pp = hv.x * fw4.x + hv.y * fw4.y + hv.z * fw4.z + hv.w * fw4.w;
            #pragma unroll
            for (int off = 8; off; off >>= 1)
                pp += __shfl_xor(pp, off, 16);
            if (fq == 0) outb[T0 + fs] = pp + fcb;
        }
    }
}

extern "C" void kernel_launch(void* const* d_in, const int* in_sizes, int n_in,
                              void* d_out, int out_size, void* d_ws, size_t ws_size,
                              hipStream_t stream) {
    const float* x    = (const float*)d_in[0];
    const float* w_ih = (const float*)d_in[1];
    const float* w_hh = (const float*)d_in[2];
    const float* b_ih = (const float*)d_in[3];
    const float* b_hh = (const float*)d_in[4];
    const float* fc_w = (const float*)d_in[5];
    const float* fc_b = (const float*)d_in[6];
    float* out = (float*)d_out;

    lstm_fused_kernel<<<Bn, 256, 0, stream>>>(x, w_ih, w_hh, b_ih, b_hh,
                                              fc_w, fc_b, out);
}

// Round 20
// 748.165 us; speedup vs baseline: 1.9905x; 1.1686x over previous
//
#include <hip/hip_runtime.h>

// Problem constants (from reference): B=256, T=2048, I=12, H=64
constexpr int Bn = 256;
constexpr int Tn = 2048;
constexpr int In = 12;
constexpr int Hn = 64;
constexpr int TCH = 512;     // steps per staged x quarter (padded to 16)
constexpr int CHUNK = 16;    // fc-flush granularity == hist depth

constexpr float LOG2E = 1.44269504088896340736f;

__device__ __forceinline__ float frcp(float v) { return __builtin_amdgcn_rcpf(v); }

// quad_perm DPP: cross-lane move within each group of 4 lanes, pure VALU.
// 0xB1 = [1,0,3,2] (xor 1), 0x4E = [2,3,0,1] (xor 2),
// 0x00/0x55/0xAA/0xFF = broadcast quad lane 0/1/2/3.
template <int CTRL>
__device__ __forceinline__ float dppq(float v) {
    int i = __float_as_int(v);
    i = __builtin_amdgcn_mov_dpp(i, CTRL, 0xF, 0xF, false);
    return __int_as_float(i);
}

// Round-20: r19's quad-K-split skeleton (no pbuf, no readlane, 1 barrier)
// with the redundancy removed:
//  - TRANSPOSE-REDUCE (12 ops) delivers gate ks's TOTAL to quad lane ks
//    (r19's full butterfly gave every lane all 4 sums -> 4 redundant
//    activations/lane = +6 trans ops on the quarter-rate pipe = r19's
//    +244 busy-cyc regression).
//  - Each lane computes ONE activation; quad_perm broadcasts i/f/g/o.
//  - x-projection for step s+1 is software-pipelined into step s's
//    act->c->tanh dependency window (h-independent work).
extern "C" __global__ void __launch_bounds__(256, 1)
lstm_fused_kernel(const float* __restrict__ x,
                  const float* __restrict__ w_ih,
                  const float* __restrict__ w_hh,
                  const float* __restrict__ b_ih,
                  const float* __restrict__ b_hh,
                  const float* __restrict__ fc_w,
                  const float* __restrict__ fc_b,
                  float* __restrict__ out)
{
    __shared__ __align__(16) float xbuf[TCH * 16];        // 32 KiB (x quarter)
    __shared__ __align__(16) float hbuf[2][Hn];           // ping-pong h
    __shared__ __align__(16) float hist[2][CHUNK][Hn];    // 8 KiB fc history

    const int tid  = threadIdx.x;       // 0..255
    const int lane = tid & 63;
    const int w    = tid >> 6;          // wave id 0..3
    const int ks   = lane & 3;          // K-slice id == owned gate id
    const int j4   = lane >> 2;         // 0..15
    const int j    = 16 * w + j4;       // owned h index
    const int b    = blockIdx.x;

    const float4* xsrc4 = (const float4*)(x + (size_t)b * Tn * In);

    // ---- zero the x padding columns (i = 12..15) once ----
    #pragma unroll
    for (int k = 0; k < 8; ++k) {
        int idx = tid + k * 256;                       // 0..2047
        xbuf[(idx >> 2) * 16 + 12 + (idx & 3)] = 0.0f;
    }

    // ---- per-lane weights: 4 gate rows of h-index j, K-slice of ks ----
    float whh_s[4][16];
    #pragma unroll
    for (int m = 0; m < 4; ++m) {
        const float4* src = (const float4*)(w_hh + (64 * m + j) * Hn + 16 * ks);
        float4 v0 = src[0], v1 = src[1], v2 = src[2], v3 = src[3];
        whh_s[m][0]=v0.x;  whh_s[m][1]=v0.y;  whh_s[m][2]=v0.z;  whh_s[m][3]=v0.w;
        whh_s[m][4]=v1.x;  whh_s[m][5]=v1.y;  whh_s[m][6]=v1.z;  whh_s[m][7]=v1.w;
        whh_s[m][8]=v2.x;  whh_s[m][9]=v2.y;  whh_s[m][10]=v2.z; whh_s[m][11]=v2.w;
        whh_s[m][12]=v3.x; whh_s[m][13]=v3.y; whh_s[m][14]=v3.z; whh_s[m][15]=v3.w;
    }
    #pragma unroll
    for (int m = 0; m < 4; ++m)
        #pragma unroll
        for (int k = 0; k < 16; k += 4)
            asm volatile("" : "+v"(whh_s[m][k+0]), "+v"(whh_s[m][k+1]),
                              "+v"(whh_s[m][k+2]), "+v"(whh_s[m][k+3]));

    float wih_s[4][4];
    if (ks < 3) {
        #pragma unroll
        for (int m = 0; m < 4; ++m) {
            float4 v = *(const float4*)(w_ih + (64 * m + j) * In + 4 * ks);
            wih_s[m][0]=v.x; wih_s[m][1]=v.y; wih_s[m][2]=v.z; wih_s[m][3]=v.w;
        }
    } else {
        #pragma unroll
        for (int m = 0; m < 4; ++m)
            wih_s[m][0]=wih_s[m][1]=wih_s[m][2]=wih_s[m][3]=0.0f;
    }
    #pragma unroll
    for (int m = 0; m < 4; ++m)
        asm volatile("" : "+v"(wih_s[m][0]), "+v"(wih_s[m][1]),
                          "+v"(wih_s[m][2]), "+v"(wih_s[m][3]));

    // bias folded into ks==0 lane's accumulator init (summed by treduce)
    float bias[4];
    #pragma unroll
    for (int m = 0; m < 4; ++m)
        bias[m] = (ks == 0) ? (b_ih[64 * m + j] + b_hh[64 * m + j]) : 0.0f;

    // own-gate activation constants (gate id == ks; gate 2 is tanh)
    const float scl  = (ks == 2) ? 2.0f : 1.0f;
    const float soff = (ks == 2) ? -1.0f : 0.0f;
    const float me   = (ks == 2) ? (-2.0f * LOG2E) : (-LOG2E);

    // fc flush constants
    const int   fq  = tid & 15;
    const int   fs  = tid >> 4;          // 0..15
    const float4 fw4 = *(const float4*)(fc_w + 4 * fq);
    const float fcb = fc_b[0];

    float c = 0.0f;                      // cell state for j (quad-redundant)
    if (tid < Hn) hbuf[1][tid] = 0.0f;   // h_{-1} = 0 (step 0 reads hbuf[1])

    float* outb = out + (size_t)b * Tn;

    float xa0, xa1, xa2, xa3;            // pipelined x+bias acc for current step

    for (int ci = 0; ci < Tn / CHUNK; ++ci) {
        const int T0  = ci * CHUNK;
        const int par = ci & 1;

        // ---- stage x quarter; recompute xa for step T0 (covers both the
        //      first chunk and the stale-prefetch at quarter boundaries) ----
        if ((T0 & (TCH - 1)) == 0) {
            const int qtr = T0 >> 9;
            #pragma unroll
            for (int k = 0; k < 6; ++k) {
                int li  = tid + k * 256;              // 0..1535 (float4s)
                int t_l = li / 3;
                int i4  = li % 3;
                ((float4*)xbuf)[t_l * 4 + i4] = xsrc4[qtr * 1536 + li];
            }
            __syncthreads();
            const float4 xv = *(const float4*)(xbuf + 4 * ks);
            xa0 = fmaf(xv.x, wih_s[0][0], bias[0]);
            xa1 = fmaf(xv.x, wih_s[1][0], bias[1]);
            xa2 = fmaf(xv.x, wih_s[2][0], bias[2]);
            xa3 = fmaf(xv.x, wih_s[3][0], bias[3]);
            xa0 = fmaf(xv.y, wih_s[0][1], xa0);  xa1 = fmaf(xv.y, wih_s[1][1], xa1);
            xa2 = fmaf(xv.y, wih_s[2][1], xa2);  xa3 = fmaf(xv.y, wih_s[3][1], xa3);
            xa0 = fmaf(xv.z, wih_s[0][2], xa0);  xa1 = fmaf(xv.z, wih_s[1][2], xa1);
            xa2 = fmaf(xv.z, wih_s[2][2], xa2);  xa3 = fmaf(xv.z, wih_s[3][2], xa3);
            xa0 = fmaf(xv.w, wih_s[0][3], xa0);  xa1 = fmaf(xv.w, wih_s[1][3], xa1);
            xa2 = fmaf(xv.w, wih_s[2][3], xa2);  xa3 = fmaf(xv.w, wih_s[3][3], xa3);
        }

        #pragma unroll
        for (int s = 0; s < CHUNK; ++s) {
            // ---- h K-slice read (uniform per 16-lane group; 2-way = free) ----
            const float4* hp = (const float4*)hbuf[(s & 1) ^ 1] + 4 * ks;
            float4 h0 = hp[0], h1 = hp[1], h2 = hp[2], h3 = hp[3];

            float a0 = xa0, a1 = xa1, a2 = xa2, a3 = xa3;
            #define HF(HV, K) \
                a0 = fmaf(HV, whh_s[0][K], a0);  a1 = fmaf(HV, whh_s[1][K], a1); \
                a2 = fmaf(HV, whh_s[2][K], a2);  a3 = fmaf(HV, whh_s[3][K], a3);
            HF(h0.x, 0)  HF(h0.y, 1)  HF(h0.z, 2)  HF(h0.w, 3)
            HF(h1.x, 4)  HF(h1.y, 5)  HF(h1.z, 6)  HF(h1.w, 7)
            HF(h2.x, 8)  HF(h2.y, 9)  HF(h2.z, 10) HF(h2.w, 11)
            HF(h3.x, 12) HF(h3.y, 13) HF(h3.z, 14) HF(h3.w, 15)
            #undef HF

            // ---- transpose-reduce: gate ks's TOTAL lands in quad lane ks ----
            float p  = (ks & 1) ? a1 : a0;
            float q  = (ks & 1) ? a0 : a1;
            p += dppq<0xB1>(q);
            float r2 = (ks & 1) ? a3 : a2;
            float s2 = (ks & 1) ? a2 : a3;
            r2 += dppq<0xB1>(s2);
            float v  = (ks & 2) ? r2 : p;
            float u  = (ks & 2) ? p : r2;
            v += dppq<0x4E>(u);

            // ---- pipeline: x-projection for step s+1 (h-independent) ----
            {
                const int tln = (T0 + s + 1) & (TCH - 1);
                const float4 xv = *(const float4*)(xbuf + tln * 16 + 4 * ks);
                xa0 = fmaf(xv.x, wih_s[0][0], bias[0]);
                xa1 = fmaf(xv.x, wih_s[1][0], bias[1]);
                xa2 = fmaf(xv.x, wih_s[2][0], bias[2]);
                xa3 = fmaf(xv.x, wih_s[3][0], bias[3]);
                xa0 = fmaf(xv.y, wih_s[0][1], xa0);  xa1 = fmaf(xv.y, wih_s[1][1], xa1);
                xa2 = fmaf(xv.y, wih_s[2][1], xa2);  xa3 = fmaf(xv.y, wih_s[3][1], xa3);
                xa0 = fmaf(xv.z, wih_s[0][2], xa0);  xa1 = fmaf(xv.z, wih_s[1][2], xa1);
                xa2 = fmaf(xv.z, wih_s[2][2], xa2);  xa3 = fmaf(xv.z, wih_s[3][2], xa3);
                xa0 = fmaf(xv.w, wih_s[0][3], xa0);  xa1 = fmaf(xv.w, wih_s[1][3], xa1);
                xa2 = fmaf(xv.w, wih_s[2][3], xa2);  xa3 = fmaf(xv.w, wih_s[3][3], xa3);
            }

            // ---- ONE activation per lane (own gate), then quad broadcast ----
            float e   = exp2f(me * v);
            float act = fmaf(scl, frcp(1.0f + e), soff);

            float iv = dppq<0x00>(act);
            float fv = dppq<0x55>(act);
            float gv = dppq<0xAA>(act);
            float ov = dppq<0xFF>(act);

            c = fmaf(fv, c, iv * gv);
            float ec = exp2f(-2.0f * LOG2E * c);
            float h  = ov * fmaf(2.0f, frcp(1.0f + ec), -1.0f);

            if (ks == 0) {
                hbuf[s & 1][j]  = h;     // recurrence publish
                hist[par][s][j] = h;     // fc history
            }
            __syncthreads();             // the ONE barrier per step
        }

        // ---- fc flush: hist[par] complete as of the last step barrier ----
        // No extra barrier: next chunk writes hist[par^1]; hist[par] is
        // rewritten only after >=17 further barriers.
        {
            const float4 hv = *(const float4*)(&hist[par][fs][4 * fq]);
            float pp = hv.x * fw4.x + hv.y * fw4.y + hv.z * fw4.z + hv.w * fw4.w;
            #pragma unroll
            for (int off = 8; off; off >>= 1)
                pp += __shfl_xor(pp, off, 16);
            if (fq == 0) outb[T0 + fs] = pp + fcb;
        }
    }
}

extern "C" void kernel_launch(void* const* d_in, const int* in_sizes, int n_in,
                              void* d_out, int out_size, void* d_ws, size_t ws_size,
                              hipStream_t stream) {
    const float* x    = (const float*)d_in[0];
    const float* w_ih = (const float*)d_in[1];
    const float* w_hh = (const float*)d_in[2];
    const float* b_ih = (const float*)d_in[3];
    const float* b_hh = (const float*)d_in[4];
    const float* fc_w = (const float*)d_in[5];
    const float* fc_b = (const float*)d_in[6];
    float* out = (float*)d_out;

    lstm_fused_kernel<<<Bn, 256, 0, stream>>>(x, w_ih, w_hh, b_ih, b_hh,
                                              fc_w, fc_b, out);
}